// Round 9
// baseline (717.742 us; speedup 1.0000x reference)
//
#include <hip/hip_runtime.h>
#include <hip/hip_bf16.h>
#include <hip/hip_fp16.h>

#define N_NODES 512
#define N_EDGES (512 * 512)
#define NBLK 256                 // sort blocks
#define EPB (N_EDGES / NBLK)     // 1024 edges per sort block
#define PADLEN 768               // padded segment length (max cnt ~630 << 768)

typedef __attribute__((ext_vector_type(8))) __bf16 bf16x8;
typedef __attribute__((ext_vector_type(16))) float f32x16;

static __device__ inline unsigned bf16rne(float f) {
    union { float f; unsigned u; } c;
    c.f = f;
    unsigned u = c.u;
    u += 0x7FFFu + ((u >> 16) & 1u);
    return u >> 16;
}
static __device__ inline float bf2f(unsigned h) {
    union { unsigned u; float f; } c;
    c.u = h << 16;
    return c.f;
}
static __device__ __forceinline__ int i4c(const int4& v, int c) {
    return c == 0 ? v.x : (c == 1 ? v.y : (c == 2 ? v.z : v.w));
}

// ---------------------------------------------------------------------------
// Counting sort by dst — no device-scope atomics.
// ---------------------------------------------------------------------------
__global__ __launch_bounds__(256) void count_kernel(const int* __restrict__ dst,
                                                    int* __restrict__ bcnt) {
    __shared__ int h[N_NODES];
    int tid = threadIdx.x;
    int b = blockIdx.x;
    h[tid] = 0;
    h[tid + 256] = 0;
    __syncthreads();
#pragma unroll
    for (int k = 0; k < EPB / 256; k++)
        atomicAdd(&h[dst[b * EPB + k * 256 + tid]], 1);
    __syncthreads();
    bcnt[b * N_NODES + tid] = h[tid];
    bcnt[b * N_NODES + tid + 256] = h[tid + 256];
}

// scan also converts the layer-1 input x (f32[512]) to half xh[512].
__global__ __launch_bounds__(512) void scan_kernel(const int* __restrict__ bcnt,
                                                   int* __restrict__ offs,
                                                   int* __restrict__ base,
                                                   const float* __restrict__ x,
                                                   __half* __restrict__ xh) {
    __shared__ int buf[N_NODES];
    int t = threadIdx.x;
    xh[t] = __float2half(x[t]);
    int sum = 0;
#pragma unroll 16
    for (int b = 0; b < NBLK; b++) sum += bcnt[b * N_NODES + t];  // coalesced rows
    buf[t] = sum;
    __syncthreads();
    for (int d = 1; d < N_NODES; d <<= 1) {
        int add = (t >= d) ? buf[t - d] : 0;
        __syncthreads();
        buf[t] += add;
        __syncthreads();
    }
    offs[t + 1] = buf[t];
    if (t == 0) offs[0] = 0;
    int run = buf[t] - sum;  // exclusive global start of bucket t
#pragma unroll 16
    for (int b = 0; b < NBLK; b++) {
        base[b * N_NODES + t] = run;
        run += bcnt[b * N_NODES + t];
    }
}

// scatter: emit padded 32B bf16 edge record at dv*PADLEN+rank, plus src id.
// k-layout: {eh0..eh5, 1.0, eh0 | eh1..eh5, 1.0, 0, 0}
__global__ __launch_bounds__(256) void scatter_kernel(const int* __restrict__ src,
                                                      const int* __restrict__ dst,
                                                      const float* __restrict__ ea,
                                                      const int* __restrict__ base,
                                                      const int* __restrict__ offs,
                                                      int4* __restrict__ edp,
                                                      int* __restrict__ srcp) {
    __shared__ int lcur[N_NODES];
    __shared__ int loff[N_NODES];
    int tid = threadIdx.x;
    int b = blockIdx.x;
    lcur[tid] = base[b * N_NODES + tid];
    lcur[tid + 256] = base[b * N_NODES + tid + 256];
    loff[tid] = offs[tid];
    loff[tid + 256] = offs[tid + 256];
    __syncthreads();
    const unsigned ONE = 0x3F80u;  // 1.0 in bf16
#pragma unroll
    for (int k = 0; k < EPB / 256; k++) {
        int e = b * EPB + k * 256 + tid;
        const float* a = ea + (size_t)e * 6;
        unsigned e0 = bf16rne(a[0]), e1 = bf16rne(a[1]), e2 = bf16rne(a[2]);
        unsigned e3 = bf16rne(a[3]), e4 = bf16rne(a[4]), e5 = bf16rne(a[5]);
        int dv = dst[e], sv = src[e];
        int p = atomicAdd(&lcur[dv], 1);  // LDS atomic, compact slot
        int rank = p - loff[dv];
        size_t pi = (size_t)dv * PADLEN + rank;
        int4 r0, r1;
        r0.x = (int)((e1 << 16) | e0);
        r0.y = (int)((e3 << 16) | e2);
        r0.z = (int)((e5 << 16) | e4);
        r0.w = (int)((e0 << 16) | ONE);   // k6 = 1.0, k7 = eh0
        r1.x = (int)((e2 << 16) | e1);
        r1.y = (int)((e4 << 16) | e3);
        r1.z = (int)((ONE << 16) | e5);   // k12 = eh5, k13 = 1.0
        r1.w = 0;
        edp[pi * 2] = r0;
        edp[pi * 2 + 1] = r1;
        srcp[pi] = sv;
    }
}

// W prepack, i-major padded layout: j'' = i*OSL + o (o < cout real, else 0).
// Per (tile t, lane): 8 bf16 = W~[k = hi*8 + 0..7][j'' = t*32+col].
// W~ rows: k0..5 = Wh[v], k6 = be_hi, k7 = Wl0, k8..12 = Wl1..5, k13 = be_lo.
__global__ __launch_bounds__(256) void wprep_kernel(const float* __restrict__ We,
                                                    const float* __restrict__ be,
                                                    int cin, int cout, int osl,
                                                    int total, int4* __restrict__ wtg) {
    int idx = blockIdx.x * 256 + threadIdx.x;
    if (idx >= total) return;
    int t = idx >> 6, lane = idx & 63, col = lane & 31, hi = lane >> 5;
    int jpp = t * 32 + col;
    int i = jpp / osl, o = jpp % osl;
    int Jr = cin * cout;
    unsigned h[8] = {0, 0, 0, 0, 0, 0, 0, 0};
    if (o < cout && i < cin) {
        int j = i * cout + o;
        unsigned wh[6];
        float wl[6];
        for (int v = 0; v < 6; v++) {
            float wv = We[v * Jr + j];
            wh[v] = bf16rne(wv);
            wl[v] = wv - bf2f(wh[v]);
        }
        float bev = be[j];
        unsigned bh = bf16rne(bev);
        float bl = bev - bf2f(bh);
        if (hi == 0) {
            for (int v = 0; v < 6; v++) h[v] = wh[v];
            h[6] = bh;
            h[7] = bf16rne(wl[0]);
        } else {
            for (int v = 1; v < 6; v++) h[v - 1] = bf16rne(wl[v]);
            h[5] = bf16rne(bl);
        }
    }
    int4 r;
    r.x = (int)((h[1] << 16) | h[0]);
    r.y = (int)((h[3] << 16) | h[2]);
    r.z = (int)((h[5] << 16) | h[4]);
    r.w = (int)((h[7] << 16) | h[6]);
    wtg[idx] = r;
}

// ---------------------------------------------------------------------------
// NNConv layer via MFMA, D = W~ · EA^T orientation: per lane, col = EDGE
// (fixed), 16 rows = j''s. i-major W layout (OSL pow2 >= COUT) makes
// i = (t*32 + (r&3)+8(r>>2)) / OSL hi-free & compile-time -> epilogue is
// acc[a] += relu(ct[r]) * xf[i]: 2 VALU/value, zero loads, zero dyn-index.
// o recovered at emit: o = (class % OSL) + 4*hi; half-wave butterfly + LDS
// atomic. Pad-o columns have W==0 -> relu(0)=0 -> contribute nothing.
// ---------------------------------------------------------------------------
template <int CIN, int COUT, int TILES, int OSL, int PIN, int POUT>
__global__ __launch_bounds__(512, 4) void nnconv_mfma(
    const float* __restrict__ hprev,  // [512*CIN] f32 (root term)
    const __half* __restrict__ hhin,  // [512*PIN] half (gather source)
    const int4* __restrict__ edp,     // padded edge records
    const int* __restrict__ srcp,     // padded src ids
    const int* __restrict__ offs,     // [513]
    const int4* __restrict__ wtg,     // [TILES*64]
    const float* __restrict__ root,   // [CIN*COUT]
    const float* __restrict__ bias,   // [COUT]
    float* __restrict__ hout,         // [512*COUT] f32
    __half* __restrict__ hhout)       // [512*POUT] half (or unused)
{
    constexpr int TPI = (OSL + 31) / 32;  // tiles per i (only >1 when OSL>32)
    constexpr int NACC = TPI * 16;
    __shared__ int4 wl[TILES * 64];
    __shared__ float lagg[COUT];

    const int tid = threadIdx.x;
    const int n = blockIdx.x;
    for (int k = tid; k < TILES * 64; k += 512) wl[k] = wtg[k];
    if (tid < COUT) lagg[tid] = 0.f;
    __syncthreads();

    const int w = tid >> 6, lane = tid & 63;
    const int col = lane & 31, hi = lane >> 5;
    const char* wlp = (const char*)wl + (hi * 32 + col) * 16;

    f32x16 zc;
#pragma unroll
    for (int q = 0; q < 16; q++) zc[q] = 0.f;

    float acc[NACC];
#pragma unroll
    for (int a = 0; a < NACC; a++) acc[a] = 0.f;

    const int nb = n * PADLEN + w * 96;

#pragma unroll 1
    for (int c = 0; c < 3; c++) {
        const int cb = nb + c * 32;
        // B operand: this lane's edge record k-section (col = edge, hi = k-half)
        bf16x8 bfrag = *(const bf16x8*)((const char*)edp + (size_t)(cb + col) * 32 + hi * 16);
        int sv = srcp[cb + col] & 511;
        // x row of this lane's edge -> registers (compile-time indexed)
        float xf[CIN];
        if constexpr (CIN == 1) {
            xf[0] = __half2float(hhin[sv]);
        } else {
            constexpr int NV4 = PIN / 8;
            const int4* hp = (const int4*)(hhin + sv * PIN);
            int4 xr[NV4];
#pragma unroll
            for (int q = 0; q < NV4; q++) xr[q] = hp[q];
#pragma unroll
            for (int i = 0; i < CIN; i++) {
                union { int d; __half2 h; } u;
                u.d = i4c(xr[i >> 3], (i >> 1) & 3);
                xf[i] = __half2float((i & 1) ? u.h.y : u.h.x);
            }
        }
#pragma unroll
        for (int t = 0; t < TILES; t++) {
            bf16x8 afrag = *(const bf16x8*)(wlp + t * 1024);  // A = W~ tile
            f32x16 ct = __builtin_amdgcn_mfma_f32_32x32x16_bf16(afrag, bfrag, zc, 0, 0, 0);
#pragma unroll
            for (int r = 0; r < 16; r++) {
                const int jlb = (r & 3) + 8 * (r >> 2);
                const int i = (t * 32 + jlb) / OSL;   // compile-time, hi-free
                const int a = (t % TPI) * 16 + r;
                acc[a] = fmaf(fmaxf(ct[r], 0.f), xf[i], acc[a]);
            }
        }
    }

    // emit: half-wave butterfly (32 lanes share o), then one LDS atomic
#pragma unroll
    for (int a = 0; a < NACC; a++) {
        const int tm = a >> 4, r = a & 15;
        const int jlb = (r & 3) + 8 * (r >> 2);
        const int ob = (tm * 32 + jlb) % OSL;  // compile-time
        float v = acc[a];
        v += __shfl_xor(v, 1);
        v += __shfl_xor(v, 2);
        v += __shfl_xor(v, 4);
        v += __shfl_xor(v, 8);
        v += __shfl_xor(v, 16);
        int o = ob + 4 * hi;
        if ((lane & 31) == 0 && o < COUT) atomicAdd(&lagg[o], v);
    }
    __syncthreads();

    if (tid < COUT) {
        int cnt = offs[n + 1] - offs[n];
        float v = lagg[tid] / fmaxf((float)cnt, 1.f);
#pragma unroll
        for (int i = 0; i < CIN; i++)
            v = fmaf(hprev[n * CIN + i], root[i * COUT + tid], v);
        v = fmaxf(v + bias[tid], 0.f);
        hout[n * COUT + tid] = v;
        if constexpr (POUT > 0) hhout[n * POUT + tid] = __float2half(v);
    } else {
        if constexpr (POUT > 0) {
            if (tid < POUT) hhout[n * POUT + tid] = __float2half(0.f);
        }
    }
}

// ---------------------------------------------------------------------------
// CBT: out[i,j] = sum_k |h3[i,k] - h3[j,k]|, h3 is [512,5]
// ---------------------------------------------------------------------------
__global__ __launch_bounds__(256) void cbt_kernel(const float* __restrict__ h3,
                                                  float* __restrict__ out) {
    __shared__ float lh[N_NODES * 5];
    int tid = threadIdx.x;
    for (int idx = tid; idx < N_NODES * 5; idx += 256) lh[idx] = h3[idx];
    __syncthreads();
    int i = blockIdx.x;
    float hi[5];
#pragma unroll
    for (int k = 0; k < 5; k++) hi[k] = lh[i * 5 + k];
    for (int j = tid; j < N_NODES; j += 256) {
        float sacc = 0.f;
#pragma unroll
        for (int k = 0; k < 5; k++) sacc += fabsf(hi[k] - lh[j * 5 + k]);
        out[i * N_NODES + j] = sacc;
    }
}

// ---------------------------------------------------------------------------
extern "C" void kernel_launch(void* const* d_in, const int* in_sizes, int n_in,
                              void* d_out, int out_size, void* d_ws, size_t ws_size,
                              hipStream_t stream) {
    const float* x = (const float*)d_in[0];
    const float* edge_attr = (const float*)d_in[1];
    const int* edge_index = (const int*)d_in[2];
    const float* We1 = (const float*)d_in[3];
    const float* be1 = (const float*)d_in[4];
    const float* root1 = (const float*)d_in[5];
    const float* b1 = (const float*)d_in[6];
    const float* We2 = (const float*)d_in[7];
    const float* be2 = (const float*)d_in[8];
    const float* root2 = (const float*)d_in[9];
    const float* b2 = (const float*)d_in[10];
    const float* We3 = (const float*)d_in[11];
    const float* be3 = (const float*)d_in[12];
    const float* root3 = (const float*)d_in[13];
    const float* b3 = (const float*)d_in[14];

    const int E = N_EDGES;
    const int* src = edge_index;
    const int* dst = edge_index + E;

    char* ws = (char*)d_ws;
    int* offs = (int*)(ws + 0);                // 513 ints (pad to 4096)
    int* bcnt = (int*)(ws + 4096);             // 256*512 -> 528384
    int* base = (int*)(ws + 528384);           // 256*512 -> 1052672
    int4* edp = (int4*)(ws + 1052672);         // 512*768*32B -> 13635584
    int* srcp = (int*)(ws + 13635584);         // 512*768*4  -> 15208448
    int4* wtg1 = (int4*)(ws + 15208448);       // 2*64*16   -> 15210496
    int4* wtg2 = (int4*)(ws + 15210496);       // 36*64*16  -> 15247360
    int4* wtg3 = (int4*)(ws + 15247360);       // 6*64*16   -> 15253504
    float* h1 = (float*)(ws + 15253504);       // 512*36*4 -> 15327232
    float* h2 = (float*)(ws + 15327232);       // 512*24*4 -> 15376384
    float* h3 = (float*)(ws + 15376384);       // 512*5*4  -> 15386624
    __half* xh = (__half*)(ws + 15386624);     // 512*2    -> 15387648
    __half* hh1 = (__half*)(ws + 15387648);    // 512*40*2 -> 15428608
    __half* hh2 = (__half*)(ws + 15428608);    // 512*24*2 -> 15453184

    // zero pad records + pad srcs (edp and srcp contiguous)
    hipMemsetAsync(edp, 0, (size_t)N_NODES * PADLEN * 32 + (size_t)N_NODES * PADLEN * 4, stream);

    count_kernel<<<NBLK, 256, 0, stream>>>(dst, bcnt);
    scan_kernel<<<1, 512, 0, stream>>>(bcnt, offs, base, x, xh);
    scatter_kernel<<<NBLK, 256, 0, stream>>>(src, dst, edge_attr, base, offs, edp, srcp);

    wprep_kernel<<<1, 256, 0, stream>>>(We1, be1, 1, 36, 64, 2 * 64, wtg1);
    wprep_kernel<<<9, 256, 0, stream>>>(We2, be2, 36, 24, 32, 36 * 64, wtg2);
    wprep_kernel<<<2, 256, 0, stream>>>(We3, be3, 24, 5, 8, 6 * 64, wtg3);

    // L1: CIN=1, COUT=36, OSL=64 (2 tiles), in-pitch 1, out-pitch 40
    nnconv_mfma<1, 36, 2, 64, 1, 40><<<N_NODES, 512, 0, stream>>>(
        x, xh, edp, srcp, offs, wtg1, root1, b1, h1, hh1);
    // L2: CIN=36, COUT=24, OSL=32 (36 tiles), in-pitch 40, out-pitch 24
    nnconv_mfma<36, 24, 36, 32, 40, 24><<<N_NODES, 512, 0, stream>>>(
        h1, hh1, edp, srcp, offs, wtg2, root2, b2, h2, hh2);
    // L3: CIN=24, COUT=5, OSL=8 (6 tiles), in-pitch 24, no half output
    nnconv_mfma<24, 5, 6, 8, 24, 0><<<N_NODES, 512, 0, stream>>>(
        h2, hh2, edp, srcp, offs, wtg3, root3, b3, h3, (__half*)nullptr);

    cbt_kernel<<<N_NODES, 256, 0, stream>>>(h3, (float*)d_out);
}